// Round 16
// baseline (169.743 us; speedup 1.0000x reference)
//
#include <hip/hip_runtime.h>

#define BATCH 4
#define SEQ   2048
#define EMB   512
#define HEADS 8
#define HD    64

typedef _Float16 half2_t __attribute__((ext_vector_type(2)));
typedef _Float16 half4_t __attribute__((ext_vector_type(4)));
typedef _Float16 half8_t __attribute__((ext_vector_type(8)));
typedef float    f32x4   __attribute__((ext_vector_type(4)));

#if __has_builtin(__builtin_amdgcn_exp2f)
#define EXP2F(x) __builtin_amdgcn_exp2f(x)
#else
#define EXP2F(x) exp2f(x)
#endif
#define LOG2E 1.44269504088896f

#define PKRTZ(a, b) __builtin_bit_cast(half2_t, __builtin_amdgcn_cvt_pkrtz((a), (b)))

// ---------------------------------------------------------------- mod factor
__global__ void mod_kernel(const float* __restrict__ emo, float* __restrict__ modv){
    int lane = threadIdx.x;                 // 64 threads, 1 wave
    for (int b = 0; b < BATCH; ++b){
        float v = emo[b*64 + lane];
        #pragma unroll
        for (int off = 32; off >= 1; off >>= 1) v += __shfl_xor(v, off, 64);
        if (lane == 0){
            float mean = v * (1.0f/64.0f);
            float sig  = 1.0f/(1.0f + __expf(-mean));
            modv[b] = 0.5f + 0.5f*sig;
        }
    }
}

// packed f32->f16 converts (RTZ; staging-only, <=1 ulp f16)
__device__ inline half8_t cvt8pk(float4 v0, float4 v1){
    half2_t p0 = PKRTZ(v0.x, v0.y), p1 = PKRTZ(v0.z, v0.w);
    half2_t p2 = PKRTZ(v1.x, v1.y), p3 = PKRTZ(v1.z, v1.w);
    half4_t a = __builtin_shufflevector(p0, p1, 0, 1, 2, 3);
    half4_t b = __builtin_shufflevector(p2, p3, 0, 1, 2, 3);
    return __builtin_shufflevector(a, b, 0, 1, 2, 3, 4, 5, 6, 7);
}
__device__ inline half8_t cvt8(const float* p){
    return cvt8pk(*(const float4*)p, *(const float4*)(p + 4));
}

// --------------------------------------- QKV projections, one launch (z=0,1,2)
// (unchanged from R15 — verified)
__global__ __launch_bounds__(256) void qkv_kernel(
    const float* __restrict__ X0, const float* __restrict__ X1, const float* __restrict__ X2,
    const float* __restrict__ W0, const float* __restrict__ W1, const float* __restrict__ W2,
    const float* __restrict__ b0, const float* __restrict__ b1, const float* __restrict__ b2,
    _Float16* __restrict__ o0, _Float16* __restrict__ o1, _Float16* __restrict__ o2)
{
    const int z = blockIdx.z;
    const float* X    = (z==0) ? X0 : (z==1) ? X1 : X2;
    const float* W    = (z==0) ? W0 : (z==1) ? W1 : W2;
    const float* bias = (z==0) ? b0 : (z==1) ? b1 : b2;
    _Float16*  out    = (z==0) ? o0 : (z==1) ? o1 : o2;

    __shared__ _Float16 lA[128*64];       // 16 KB row-major, swizzled chunks
    __shared__ _Float16 lB[64*64];        //  8 KB

    const int tid  = threadIdx.x;
    const int wid  = tid >> 6;
    const int lane = tid & 63;
    const int l16  = lane & 15;
    const int g    = lane >> 4;
    const int l7   = l16 & 7;
    const int mb = blockIdx.x;
    const int nb = blockIdx.y;
    const int wm = (wid >> 1)*64;
    const int wn = (wid & 1)*32;
    const int tR = tid >> 3;
    const int c8 = tid & 7;

    #pragma unroll
    for (int p = 0; p < 4; ++p){
        const int R = p*32 + tR;
        *(half8_t*)(lA + R*64 + ((c8 ^ (R & 7))*8)) = cvt8(X + (size_t)(mb*128 + R)*EMB + c8*8);
    }
    #pragma unroll
    for (int p = 0; p < 2; ++p){
        const int R = p*32 + tR;
        *(half8_t*)(lB + R*64 + ((c8 ^ (R & 7))*8)) = cvt8(W + (size_t)(nb*64 + R)*EMB + c8*8);
    }
    __syncthreads();

    f32x4 acc[4][2] = {};
    for (int ks = 0; ks < 8; ++ks){
        float4 xa0[4], xa1[4], wb0[2], wb1[2];
        if (ks < 7){
            #pragma unroll
            for (int p = 0; p < 4; ++p){
                const float* px = X + (size_t)(mb*128 + p*32 + tR)*EMB + (ks+1)*64 + c8*8;
                xa0[p] = *(const float4*)px;
                xa1[p] = *(const float4*)(px + 4);
            }
            #pragma unroll
            for (int p = 0; p < 2; ++p){
                const float* pw = W + (size_t)(nb*64 + p*32 + tR)*EMB + (ks+1)*64 + c8*8;
                wb0[p] = *(const float4*)pw;
                wb1[p] = *(const float4*)(pw + 4);
            }
        }
        __builtin_amdgcn_s_setprio(1);
        #pragma unroll
        for (int u = 0; u < 2; ++u){
            half8_t af[4], bf[2];
            #pragma unroll
            for (int i = 0; i < 4; ++i){
                const int rA = wm + i*16 + l16;
                af[i] = *(half8_t*)(lA + rA*64 + (((u*4 + g) ^ l7)*8));
            }
            #pragma unroll
            for (int j = 0; j < 2; ++j){
                const int rB = wn + j*16 + l16;
                bf[j] = *(half8_t*)(lB + rB*64 + (((u*4 + g) ^ l7)*8));
            }
            #pragma unroll
            for (int i = 0; i < 4; ++i)
                #pragma unroll
                for (int j = 0; j < 2; ++j)
                    acc[i][j] = __builtin_amdgcn_mfma_f32_16x16x32_f16(af[i], bf[j], acc[i][j], 0, 0, 0);
        }
        __builtin_amdgcn_s_setprio(0);
        __syncthreads();
        if (ks < 7){
            #pragma unroll
            for (int p = 0; p < 4; ++p){
                const int R = p*32 + tR;
                *(half8_t*)(lA + R*64 + ((c8 ^ (R & 7))*8)) = cvt8pk(xa0[p], xa1[p]);
            }
            #pragma unroll
            for (int p = 0; p < 2; ++p){
                const int R = p*32 + tR;
                *(half8_t*)(lB + R*64 + ((c8 ^ (R & 7))*8)) = cvt8pk(wb0[p], wb1[p]);
            }
            __syncthreads();
        }
    }
    #pragma unroll
    for (int j = 0; j < 2; ++j){
        const int nn  = nb*64 + wn + j*16 + l16;
        const float bn = bias[nn];
        const int h = nn >> 6, d = nn & 63;
        #pragma unroll
        for (int i = 0; i < 4; ++i){
            #pragma unroll
            for (int r = 0; r < 4; ++r){
                const int m  = mb*128 + wm + i*16 + 4*g + r;
                const int bb2 = m >> 11, s = m & 2047;
                const int bh  = bb2*8 + h;
                const float v = acc[i][j][r] + bn;
                size_t idx;
                if (z == 2)
                    idx = ((size_t)(bh*128 + (s>>4))*2 + (d>>5))*512
                        + (size_t)((((s>>2)&3)*16 + (d&15))*8 + ((d>>4)&1)*4 + (s&3));
                else
                    idx = ((size_t)(bh*128 + (s>>4))*2 + (d>>5))*512
                        + (size_t)((((d>>3)&3)*16 + (s&15))*8 + (d&7));
                out[idx] = (_Float16)v;
            }
        }
    }
}

// ---------------------------------------------------- pass 1: PV partials (K-split x2)
// Grid 2048: (bh, qt, kh). Each block does 1024 keys as 32 groups of 32 keys;
// dbuf LDS = 16 KB -> 8 blocks/CU resident (100% wave cap, was 50%). Structure
// identical to R15's verified dbuf loop, t<2. Writes UNNORMALIZED partials:
// PA[kh][bh*SEQ+q][64] f32 and PL[kh][bh*SEQ+q]; combine_kernel finishes.
__global__ __launch_bounds__(256) void pv_kernel(
    const _Float16* __restrict__ Qf, const _Float16* __restrict__ Kf,
    const _Float16* __restrict__ Vf, const float* __restrict__ emo_bias,
    const float* __restrict__ modv, float* __restrict__ PA,
    float* __restrict__ PL)
{
    __shared__ _Float16 lK[2][2048];      // 2 x 4 KB
    __shared__ _Float16 lV[2][2048];      // 2 x 4 KB

    const int tid  = threadIdx.x;
    const int lane = tid & 63;
    const int l16  = lane & 15;
    const int g    = lane >> 4;
    const int n    = blockIdx.x;
    const int work = (n & 7)*256 + (n >> 3);   // bijective for 2048 blocks
    const int kh   = work & 1;                 // K-half
    const int qt   = (work >> 1) & 31;
    const int bh   = work >> 6;                // [0,32)
    const int b    = bh >> 3, h = bh & 7;
    const int q0   = qt*64 + (tid >> 6)*16;

    const float mod = modv[b];
    const float sm2 = 0.125f * mod * LOG2E;
    const float bm2 = emo_bias[h] * mod * LOG2E;

    const size_t fB = (size_t)bh * 128;
    const int tb0 = kh * 64;                   // first 16-key tile of this half

    half8_t qf[2];
    #pragma unroll
    for (int c = 0; c < 2; ++c)
        qf[c] = *(const half8_t*)(Qf + ((fB + (q0>>4))*2 + c)*512 + lane*8);

    {   // prologue: stage group 0 (4 KB K + 4 KB V, one half8 each)
        *(half8_t*)(&lK[0][tid*8]) = *(const half8_t*)(Kf + (fB + tb0)*1024 + tid*8);
        *(half8_t*)(&lV[0][tid*8]) = *(const half8_t*)(Vf + (fB + tb0)*1024 + tid*8);
    }
    __syncthreads();

    const half4_t ones4 = {(_Float16)1.0f, (_Float16)1.0f, (_Float16)1.0f, (_Float16)1.0f};
    f32x4 acc[4] = {};
    f32x4 acc5 = {};                      // partial rowsums
    int cur = 0;
    for (int grp = 0; grp < 32; ++grp){
        half8_t rk, rv;
        if (grp < 31){
            rk = *(const half8_t*)(Kf + (fB + tb0 + (grp+1)*2)*1024 + tid*8);
            rv = *(const half8_t*)(Vf + (fB + tb0 + (grp+1)*2)*1024 + tid*8);
        }
        const _Float16* kb = &lK[cur][0];
        const _Float16* vb = &lV[cur][0];
        f32x4 s[2];
        __builtin_amdgcn_s_setprio(1);
        #pragma unroll
        for (int t = 0; t < 2; ++t){
            half8_t k0 = *(const half8_t*)(kb + (t*2+0)*512 + lane*8);
            half8_t k1 = *(const half8_t*)(kb + (t*2+1)*512 + lane*8);
            f32x4 zz = {};
            zz = __builtin_amdgcn_mfma_f32_16x16x32_f16(k0, qf[0], zz, 0, 0, 0);
            zz = __builtin_amdgcn_mfma_f32_16x16x32_f16(k1, qf[1], zz, 0, 0, 0);
            s[t] = zz;
        }
        __builtin_amdgcn_s_setprio(0);
        half4_t pf[2];
        #pragma unroll
        for (int t = 0; t < 2; ++t){
            float e0 = EXP2F(s[t][0]*sm2 + bm2);
            float e1 = EXP2F(s[t][1]*sm2 + bm2);
            float e2 = EXP2F(s[t][2]*sm2 + bm2);
            float e3 = EXP2F(s[t][3]*sm2 + bm2);
            half2_t plo = PKRTZ(e0, e1), phi = PKRTZ(e2, e3);
            pf[t] = __builtin_shufflevector(plo, phi, 0, 1, 2, 3);
        }
        __builtin_amdgcn_s_setprio(1);
        #pragma unroll
        for (int t = 0; t < 2; ++t){
            half8_t vp0 = *(const half8_t*)(vb + (t*2+0)*512 + lane*8);
            half8_t vp1 = *(const half8_t*)(vb + (t*2+1)*512 + lane*8);
            half4_t v0 = __builtin_shufflevector(vp0, vp0, 0, 1, 2, 3);
            half4_t v1 = __builtin_shufflevector(vp0, vp0, 4, 5, 6, 7);
            half4_t v2 = __builtin_shufflevector(vp1, vp1, 0, 1, 2, 3);
            half4_t v3 = __builtin_shufflevector(vp1, vp1, 4, 5, 6, 7);
            acc5   = __builtin_amdgcn_mfma_f32_16x16x16f16(pf[t], ones4, acc5, 0, 0, 0);
            acc[0] = __builtin_amdgcn_mfma_f32_16x16x16f16(pf[t], v0, acc[0], 0, 0, 0);
            acc[1] = __builtin_amdgcn_mfma_f32_16x16x16f16(pf[t], v1, acc[1], 0, 0, 0);
            acc[2] = __builtin_amdgcn_mfma_f32_16x16x16f16(pf[t], v2, acc[2], 0, 0, 0);
            acc[3] = __builtin_amdgcn_mfma_f32_16x16x16f16(pf[t], v3, acc[3], 0, 0, 0);
        }
        __builtin_amdgcn_s_setprio(0);
        if (grp < 31){
            *(half8_t*)(&lK[cur^1][tid*8]) = rk;
            *(half8_t*)(&lV[cur^1][tid*8]) = rv;
        }
        __syncthreads();
        cur ^= 1;
    }

    // partial writes: row = bh*SEQ + q, q = q0+4g+r
    const size_t base = (size_t)kh * (32u*SEQ) ;   // kh row-offset (32*2048 rows)
    #pragma unroll
    for (int r = 0; r < 4; ++r){
        const size_t row = base + (size_t)bh*SEQ + q0 + 4*g + r;
        #pragma unroll
        for (int c = 0; c < 4; ++c)
            PA[row*64 + 16*c + l16] = acc[c][r];
        if (l16 == 0) PL[row] = acc5[r];
    }
}

// ------------------------------------ combine: attended = (A0+A1)/(L0+L1)
// Streaming; also writes Ldenom = L0+L1 for mean_kernel.
__global__ __launch_bounds__(256) void combine_kernel(
    const float* __restrict__ PA, const float* __restrict__ PL,
    _Float16* __restrict__ attended, float* __restrict__ Ldenom)
{
    const size_t NROW = (size_t)BATCH*HEADS*SEQ;       // 65536
    const size_t gid  = (size_t)blockIdx.x*256 + threadIdx.x;
    const size_t base = gid*8;                          // 8 d-elems per thread
    const size_t row  = base >> 6;
    const int    d0   = (int)(base & 63);
    if (row >= NROW) return;
    const int bh = (int)(row >> 11), q = (int)(row & 2047);
    const int b = bh >> 3, h = bh & 7;

    const float L = PL[row] + PL[NROW + row];
    const float inv = 1.0f / L;
    float4 a0 = *(const float4*)(PA + row*64 + d0);
    float4 a1 = *(const float4*)(PA + row*64 + d0 + 4);
    float4 b0 = *(const float4*)(PA + NROW*64 + row*64 + d0);
    float4 b1 = *(const float4*)(PA + NROW*64 + row*64 + d0 + 4);
    float4 s0, s1;
    s0.x=(a0.x+b0.x)*inv; s0.y=(a0.y+b0.y)*inv; s0.z=(a0.z+b0.z)*inv; s0.w=(a0.w+b0.w)*inv;
    s1.x=(a1.x+b1.x)*inv; s1.y=(a1.y+b1.y)*inv; s1.z=(a1.z+b1.z)*inv; s1.w=(a1.w+b1.w)*inv;
    *(half8_t*)(attended + ((size_t)(b*SEQ + q))*EMB + h*64 + d0) = cvt8pk(s0, s1);
    if (d0 == 0) Ldenom[row] = L;
}

// ------------------------------------------- pass 2: softmax mean over heads
// (unchanged from R15 — verified)
__global__ __launch_bounds__(256) void mean_kernel(
    const _Float16* __restrict__ Qf, const _Float16* __restrict__ Kf,
    const float* __restrict__ emo_bias, const float* __restrict__ modv,
    const float* __restrict__ Ldenom, float* __restrict__ mean_out)
{
    const int tid  = threadIdx.x;
    const int w    = tid >> 6;
    const int lane = tid & 63;
    const int l16  = lane & 15;
    const int g    = lane >> 4;
    const int n    = blockIdx.x;
    const int work = (n & 7)*256 + (n >> 3);
    const int b    = work >> 9;
    const int ky   = (work >> 6) & 7;
    const int qt   = work & 63;
    const int q0   = qt * 32;
    const int k0w  = ky*256 + w*64;

    const float mod = modv[b];
    const float sm2 = 0.125f * mod * LOG2E;

    f32x4 msum[2][4] = {};
    for (int hp = 0; hp < HEADS/2; ++hp){
        const int h0 = 2*hp, h1 = 2*hp + 1;
        const size_t lo0 = (size_t)(b*HEADS + h0) * SEQ;
        const size_t lo1 = (size_t)(b*HEADS + h1) * SEQ;
        const size_t f0  = (size_t)(b*HEADS + h0) * 128;
        const size_t f1  = (size_t)(b*HEADS + h1) * 128;
        const float bm20 = emo_bias[h0] * mod * LOG2E;
        const float bm21 = emo_bias[h1] * mod * LOG2E;
        half8_t qA[2][2], qB[2][2];
        float elA[2][4], elB[2][4];
        #pragma unroll
        for (int T = 0; T < 2; ++T){
            const int qr = q0 + T*16;
            #pragma unroll
            for (int c = 0; c < 2; ++c){
                qA[T][c] = *(const half8_t*)(Qf + ((f0 + (qr>>4))*2 + c)*512 + lane*8);
                qB[T][c] = *(const half8_t*)(Qf + ((f1 + (qr>>4))*2 + c)*512 + lane*8);
            }
            #pragma unroll
            for (int r = 0; r < 4; ++r){
                elA[T][r] = bm20 - __log2f(Ldenom[lo0 + qr + 4*g + r]);
                elB[T][r] = bm21 - __log2f(Ldenom[lo1 + qr + 4*g + r]);
            }
        }
        #pragma unroll
        for (int j = 0; j < 4; ++j){
            const int kc = (k0w >> 4) + j;
            half8_t ka0 = *(const half8_t*)(Kf + ((f0 + kc)*2 + 0)*512 + lane*8);
            half8_t ka1 = *(const half8_t*)(Kf + ((f0 + kc)*2 + 1)*512 + lane*8);
            half8_t kb0 = *(const half8_t*)(Kf + ((f1 + kc)*2 + 0)*512 + lane*8);
            half8_t kb1 = *(const half8_t*)(Kf + ((f1 + kc)*2 + 1)*512 + lane*8);
            #pragma unroll
            for (int T = 0; T < 2; ++T){
                f32x4 sA = {}, sB = {};
                sA = __builtin_amdgcn_mfma_f32_16x16x32_f16(qA[T][0], ka0, sA, 0, 0, 0);
                sA = __builtin_amdgcn_mfma_f32_16x16x32_f16(qA[T][1], ka1, sA, 0, 0, 0);
                sB = __builtin_amdgcn_mfma_f32_16x16x32_f16(qB[T][0], kb0, sB, 0, 0, 0);
                sB = __builtin_amdgcn_mfma_f32_16x16x32_f16(qB[T][1], kb1, sB, 0, 0, 0);
                #pragma unroll
                for (int r = 0; r < 4; ++r)
                    msum[T][j][r] += EXP2F(sA[r]*sm2 + elA[T][r])
                                   + EXP2F(sB[r]*sm2 + elB[T][r]);
            }
        }
    }
    #pragma unroll
    for (int T = 0; T < 2; ++T)
        #pragma unroll
        for (int j = 0; j < 4; ++j)
            #pragma unroll
            for (int r = 0; r < 4; ++r)
                mean_out[(size_t)(b*SEQ + q0 + T*16 + 4*g + r)*SEQ + k0w + j*16 + l16]
                    = msum[T][j][r] * (1.0f/HEADS);
}

// ------------------------------------------------- output projection (LDS GEMM)
// (unchanged from R15 — verified)
__global__ __launch_bounds__(256) void outproj_kernel(
    const _Float16* __restrict__ A, const float* __restrict__ W,
    const float* __restrict__ bias, float* __restrict__ out)
{
    __shared__ _Float16 lA[128*64];
    __shared__ _Float16 lB[64*64];

    const int tid  = threadIdx.x;
    const int wid  = tid >> 6;
    const int lane = tid & 63;
    const int l16  = lane & 15;
    const int g    = lane >> 4;
    const int l7   = l16 & 7;
    const int mb = blockIdx.x;
    const int nb = blockIdx.y;
    const int wm = (wid >> 1)*64;
    const int wn = (wid & 1)*32;
    const int tR = tid >> 3;
    const int c8 = tid & 7;

    #pragma unroll
    for (int p = 0; p < 4; ++p){
        const int R = p*32 + tR;
        *(half8_t*)(lA + R*64 + ((c8 ^ (R & 7))*8)) =
            *(const half8_t*)(A + (size_t)(mb*128 + R)*EMB + c8*8);
    }
    #pragma unroll
    for (int p = 0; p < 2; ++p){
        const int R = p*32 + tR;
        *(half8_t*)(lB + R*64 + ((c8 ^ (R & 7))*8)) = cvt8(W + (size_t)(nb*64 + R)*EMB + c8*8);
    }
    __syncthreads();

    f32x4 acc[4][2] = {};
    for (int ks = 0; ks < 8; ++ks){
        half8_t ra[4];
        float4 wb0[2], wb1[2];
        if (ks < 7){
            #pragma unroll
            for (int p = 0; p < 4; ++p)
                ra[p] = *(const half8_t*)(A + (size_t)(mb*128 + p*32 + tR)*EMB + (ks+1)*64 + c8*8);
            #pragma unroll
            for (int p = 0; p < 2; ++p){
                const float* pw = W + (size_t)(nb*64 + p*32 + tR)*EMB + (ks+1)*64 + c8*8;
                wb0[p] = *(const float4*)pw;
                wb1[p] = *(const float4*)(pw + 4);
            }
        }
        __builtin_amdgcn_s_setprio(1);
        #pragma unroll
        for (int u = 0; u < 2; ++u){
            half8_t af[4], bf[2];
            #pragma unroll
            for (int i = 0; i < 4; ++i){
                const int rA = wm + i*16 + l16;
                af[i] = *(half8_t*)(lA + rA*64 + (((u*4 + g) ^ l7)*8));
            }
            #pragma unroll
            for (int j = 0; j < 2; ++j){
                const int rB = wn + j*16 + l16;
                bf[j] = *(half8_t*)(lB + rB*64 + (((u*4 + g) ^ l7)*8));
            }
            #pragma unroll
            for (int i = 0; i < 4; ++i)
                #pragma unroll
                for (int j = 0; j < 2; ++j)
                    acc[i][j] = __builtin_amdgcn_mfma_f32_16x16x32_f16(af[i], bf[j], acc[i][j], 0, 0, 0);
        }
        __builtin_amdgcn_s_setprio(0);
        __syncthreads();
        if (ks < 7){
            #pragma unroll
            for (int p = 0; p < 4; ++p){
                const int R = p*32 + tR;
                *(half8_t*)(lA + R*64 + ((c8 ^ (R & 7))*8)) = ra[p];
            }
            #pragma unroll
            for (int p = 0; p < 2; ++p){
                const int R = p*32 + tR;
                *(half8_t*)(lB + R*64 + ((c8 ^ (R & 7))*8)) = cvt8pk(wb0[p], wb1[p]);
            }
            __syncthreads();
        }
    }
    #pragma unroll
    for (int j = 0; j < 2; ++j){
        const int nn = nb*64 + wn + j*16 + l16;
        const float bn = bias[nn];
        #pragma unroll
        for (int i = 0; i < 4; ++i)
            #pragma unroll
            for (int r = 0; r < 4; ++r){
                const int m = mb*128 + wm + i*16 + 4*g + r;
                out[(size_t)m*EMB + nn] = acc[i][j][r] + bn;
            }
    }
}

// ---------------------------------------------------------------------- host
extern "C" void kernel_launch(void* const* d_in, const int* in_sizes, int n_in,
                              void* d_out, int out_size, void* d_ws, size_t ws_size,
                              hipStream_t stream)
{
    const float* query = (const float*)d_in[0];
    const float* key_  = (const float*)d_in[1];
    const float* value = (const float*)d_in[2];
    const float* emo   = (const float*)d_in[3];
    const float* Wq = (const float*)d_in[4];
    const float* bq = (const float*)d_in[5];
    const float* Wk = (const float*)d_in[6];
    const float* bk = (const float*)d_in[7];
    const float* Wv = (const float*)d_in[8];
    const float* bv = (const float*)d_in[9];
    const float* Wo = (const float*)d_in[10];
    const float* bo = (const float*)d_in[11];
    const float* emo_bias = (const float*)d_in[12];

    const size_t NTOK = (size_t)BATCH * SEQ * EMB;   // 4,194,304
    _Float16* ws       = (_Float16*)d_ws;
    _Float16* Qp       = ws;                          // ws usage: exactly 32 MiB
    _Float16* Kp       = ws + NTOK;
    _Float16* Vt       = ws + 2*NTOK;
    _Float16* attended = ws + 3*NTOK;

    float* out0     = (float*)d_out;
    float* mean_out = out0 + NTOK;
    // Scratch (all consumed before being overwritten):
    //  Ldenom: out0[0 .. 65536)           — overwritten by outproj at the end
    //  modv:   out0[65536 .. +4)
    //  PL:     out0[262144 .. +131072)    — partial rowsums (2 halves)
    //  PA:     mean_out region (33.5 MB)  — partial numerators; consumed by
    //          combine BEFORE mean_kernel overwrites mean_out
    float* Ldenom = out0;
    float* modv   = out0 + (size_t)BATCH*HEADS*SEQ;
    float* PL     = out0 + 262144;
    float* PA     = mean_out;

    mod_kernel<<<1, 64, 0, stream>>>(emo, modv);
    qkv_kernel<<<dim3(64, 8, 3), 256, 0, stream>>>(query, key_, value, Wq, Wk, Wv,
                                                   bq, bk, bv, Qp, Kp, Vt);
    pv_kernel<<<BATCH*HEADS*(SEQ/64)*2, 256, 0, stream>>>(Qp, Kp, Vt, emo_bias, modv, PA, PL);
    combine_kernel<<<(BATCH*HEADS*SEQ*HD/8 + 255)/256, 256, 0, stream>>>(PA, PL, attended, Ldenom);
    mean_kernel<<<BATCH*(SEQ/32)*(SEQ/256), 256, 0, stream>>>(Qp, Kp, emo_bias, modv, Ldenom, mean_out);
    outproj_kernel<<<dim3(64, 8), 256, 0, stream>>>(attended, Wo, bo, out0);
}

// Round 17
// 165.167 us; speedup vs baseline: 1.0277x; 1.0277x over previous
//
#include <hip/hip_runtime.h>

#define BATCH 4
#define SEQ   2048
#define EMB   512
#define HEADS 8
#define HD    64

typedef _Float16 half2_t __attribute__((ext_vector_type(2)));
typedef _Float16 half4_t __attribute__((ext_vector_type(4)));
typedef _Float16 half8_t __attribute__((ext_vector_type(8)));
typedef float    f32x4   __attribute__((ext_vector_type(4)));

#if __has_builtin(__builtin_amdgcn_exp2f)
#define EXP2F(x) __builtin_amdgcn_exp2f(x)
#else
#define EXP2F(x) exp2f(x)
#endif
#define LOG2E 1.44269504088896f

#define PKRTZ(a, b) __builtin_bit_cast(half2_t, __builtin_amdgcn_cvt_pkrtz((a), (b)))

// ---------------------------------------------------------------- mod factor
__global__ void mod_kernel(const float* __restrict__ emo, float* __restrict__ modv){
    int lane = threadIdx.x;                 // 64 threads, 1 wave
    for (int b = 0; b < BATCH; ++b){
        float v = emo[b*64 + lane];
        #pragma unroll
        for (int off = 32; off >= 1; off >>= 1) v += __shfl_xor(v, off, 64);
        if (lane == 0){
            float mean = v * (1.0f/64.0f);
            float sig  = 1.0f/(1.0f + __expf(-mean));
            modv[b] = 0.5f + 0.5f*sig;
        }
    }
}

// packed f32->f16 converts (RTZ; staging-only, <=1 ulp f16)
__device__ inline half8_t cvt8pk(float4 v0, float4 v1){
    half2_t p0 = PKRTZ(v0.x, v0.y), p1 = PKRTZ(v0.z, v0.w);
    half2_t p2 = PKRTZ(v1.x, v1.y), p3 = PKRTZ(v1.z, v1.w);
    half4_t a = __builtin_shufflevector(p0, p1, 0, 1, 2, 3);
    half4_t b = __builtin_shufflevector(p2, p3, 0, 1, 2, 3);
    return __builtin_shufflevector(a, b, 0, 1, 2, 3, 4, 5, 6, 7);
}
__device__ inline half8_t cvt8(const float* p){
    return cvt8pk(*(const float4*)p, *(const float4*)(p + 4));
}

// --------------------------------------- QKV projections, one launch (z=0,1,2)
// 128x128 block tile (4 waves of 64x64), BK=64: 32 MFMA per barrier-interval
// per wave (was 16); W-panel traffic halves. A rows (unique, HBM) prefetched
// early into regs; W rows (L2-shared across 64 blocks) loaded late in the
// staging phase. XOR-swizzled LDS + fragment-major outputs as verified R11-R15.
__global__ __launch_bounds__(256) void qkv_kernel(
    const float* __restrict__ X0, const float* __restrict__ X1, const float* __restrict__ X2,
    const float* __restrict__ W0, const float* __restrict__ W1, const float* __restrict__ W2,
    const float* __restrict__ b0, const float* __restrict__ b1, const float* __restrict__ b2,
    _Float16* __restrict__ o0, _Float16* __restrict__ o1, _Float16* __restrict__ o2)
{
    const int z = blockIdx.z;
    const float* X    = (z==0) ? X0 : (z==1) ? X1 : X2;
    const float* W    = (z==0) ? W0 : (z==1) ? W1 : W2;
    const float* bias = (z==0) ? b0 : (z==1) ? b1 : b2;
    _Float16*  out    = (z==0) ? o0 : (z==1) ? o1 : o2;

    __shared__ _Float16 lA[128*64];       // 16 KB row-major, swizzled chunks
    __shared__ _Float16 lB[128*64];       // 16 KB

    const int tid  = threadIdx.x;
    const int wid  = tid >> 6;
    const int lane = tid & 63;
    const int l16  = lane & 15;
    const int g    = lane >> 4;
    const int l7   = l16 & 7;
    const int mb = blockIdx.x;            // 64 m-tiles of 128
    const int nb = blockIdx.y;            // 4 n-tiles of 128
    const int wm = (wid >> 1)*64;
    const int wn = (wid & 1)*64;
    const int tR = tid >> 3;              // 0..31
    const int c8 = tid & 7;

    // ---- prologue: stage ks=0
    #pragma unroll
    for (int p = 0; p < 4; ++p){
        const int R = p*32 + tR;
        *(half8_t*)(lA + R*64 + ((c8 ^ (R & 7))*8)) = cvt8(X + (size_t)(mb*128 + R)*EMB + c8*8);
    }
    #pragma unroll
    for (int p = 0; p < 4; ++p){
        const int R = p*32 + tR;
        *(half8_t*)(lB + R*64 + ((c8 ^ (R & 7))*8)) = cvt8(W + (size_t)(nb*128 + R)*EMB + c8*8);
    }
    __syncthreads();

    f32x4 acc[4][4] = {};
    for (int ks = 0; ks < 8; ++ks){
        // ---- prefetch next A panel into regs (HBM-latency-critical rows)
        float4 xa0[4], xa1[4];
        if (ks < 7){
            #pragma unroll
            for (int p = 0; p < 4; ++p){
                const float* px = X + (size_t)(mb*128 + p*32 + tR)*EMB + (ks+1)*64 + c8*8;
                xa0[p] = *(const float4*)px;
                xa1[p] = *(const float4*)(px + 4);
            }
        }
        // ---- compute from LDS
        __builtin_amdgcn_s_setprio(1);
        #pragma unroll
        for (int u = 0; u < 2; ++u){
            half8_t af[4], bf[4];
            #pragma unroll
            for (int i = 0; i < 4; ++i){
                const int rA = wm + i*16 + l16;
                af[i] = *(half8_t*)(lA + rA*64 + (((u*4 + g) ^ l7)*8));
            }
            #pragma unroll
            for (int j = 0; j < 4; ++j){
                const int rB = wn + j*16 + l16;
                bf[j] = *(half8_t*)(lB + rB*64 + (((u*4 + g) ^ l7)*8));
            }
            #pragma unroll
            for (int i = 0; i < 4; ++i)
                #pragma unroll
                for (int j = 0; j < 4; ++j)
                    acc[i][j] = __builtin_amdgcn_mfma_f32_16x16x32_f16(af[i], bf[j], acc[i][j], 0, 0, 0);
        }
        __builtin_amdgcn_s_setprio(0);
        __syncthreads();          // all reads of the buffer done
        if (ks < 7){
            // issue W loads (L2-shared, short live range), write A, write B
            float4 wb0[4], wb1[4];
            #pragma unroll
            for (int p = 0; p < 4; ++p){
                const float* pw = W + (size_t)(nb*128 + p*32 + tR)*EMB + (ks+1)*64 + c8*8;
                wb0[p] = *(const float4*)pw;
                wb1[p] = *(const float4*)(pw + 4);
            }
            #pragma unroll
            for (int p = 0; p < 4; ++p){
                const int R = p*32 + tR;
                *(half8_t*)(lA + R*64 + ((c8 ^ (R & 7))*8)) = cvt8pk(xa0[p], xa1[p]);
            }
            #pragma unroll
            for (int p = 0; p < 4; ++p){
                const int R = p*32 + tR;
                *(half8_t*)(lB + R*64 + ((c8 ^ (R & 7))*8)) = cvt8pk(wb0[p], wb1[p]);
            }
            __syncthreads();      // buffer refilled
        }
    }
    // ---- store (fragment-major out, mapping identical to R10-R15)
    #pragma unroll
    for (int j = 0; j < 4; ++j){
        const int nn  = nb*128 + wn + j*16 + l16;
        const float bn = bias[nn];
        const int h = nn >> 6, d = nn & 63;
        #pragma unroll
        for (int i = 0; i < 4; ++i){
            #pragma unroll
            for (int r = 0; r < 4; ++r){
                const int m  = mb*128 + wm + i*16 + 4*g + r;
                const int bb2 = m >> 11, s = m & 2047;
                const int bh  = bb2*8 + h;
                const float v = acc[i][j][r] + bn;
                size_t idx;
                if (z == 2)
                    idx = ((size_t)(bh*128 + (s>>4))*2 + (d>>5))*512
                        + (size_t)((((s>>2)&3)*16 + (d&15))*8 + ((d>>4)&1)*4 + (s&3));
                else
                    idx = ((size_t)(bh*128 + (s>>4))*2 + (d>>5))*512
                        + (size_t)((((d>>3)&3)*16 + (s&15))*8 + (d&7));
                out[idx] = (_Float16)v;
            }
        }
    }
}

// ---------------------------------------------------- pass 1: PV + denominators
// (reverted to R15 — verified; best measured variant)
__global__ __launch_bounds__(256) void pv_kernel(
    const _Float16* __restrict__ Qf, const _Float16* __restrict__ Kf,
    const _Float16* __restrict__ Vf, const float* __restrict__ emo_bias,
    const float* __restrict__ modv, _Float16* __restrict__ attended,
    float* __restrict__ Ldenom)
{
    __shared__ _Float16 lK[2][4096];      // 2 x 8 KB
    __shared__ _Float16 lV[2][4096];      // 2 x 8 KB

    const int tid  = threadIdx.x;
    const int lane = tid & 63;
    const int l16  = lane & 15;
    const int g    = lane >> 4;
    const int n    = blockIdx.x;
    const int work = (n & 7)*128 + (n >> 3);   // bijective for 1024 blocks
    const int qt   = work & 31;
    const int bh   = work >> 5;
    const int b    = bh >> 3, h = bh & 7;
    const int q0   = qt*64 + (tid >> 6)*16;

    const float mod = modv[b];
    const float sm2 = 0.125f * mod * LOG2E;
    const float bm2 = emo_bias[h] * mod * LOG2E;

    const size_t fB = (size_t)bh * 128;

    half8_t qf[2];
    #pragma unroll
    for (int c = 0; c < 2; ++c)
        qf[c] = *(const half8_t*)(Qf + ((fB + (q0>>4))*2 + c)*512 + lane*8);

    {   // prologue: lane-linear staging of group 0
        const _Float16* gk = Kf + fB*1024;
        const _Float16* gv = Vf + fB*1024;
        *(half8_t*)(&lK[0][tid*8])        = *(const half8_t*)(gk + tid*8);
        *(half8_t*)(&lK[0][2048 + tid*8]) = *(const half8_t*)(gk + 2048 + tid*8);
        *(half8_t*)(&lV[0][tid*8])        = *(const half8_t*)(gv + tid*8);
        *(half8_t*)(&lV[0][2048 + tid*8]) = *(const half8_t*)(gv + 2048 + tid*8);
    }
    __syncthreads();

    const half4_t ones4 = {(_Float16)1.0f, (_Float16)1.0f, (_Float16)1.0f, (_Float16)1.0f};
    f32x4 acc[4] = {};
    f32x4 acc5 = {};                      // rowsums (softmax denominators)
    int cur = 0;
    for (int grp = 0; grp < SEQ/64; ++grp){
        half8_t rk0, rk1, rv0, rv1;
        if (grp < SEQ/64 - 1){
            const _Float16* gk = Kf + (fB + (size_t)(grp+1)*4)*1024;
            const _Float16* gv = Vf + (fB + (size_t)(grp+1)*4)*1024;
            rk0 = *(const half8_t*)(gk + tid*8);
            rk1 = *(const half8_t*)(gk + 2048 + tid*8);
            rv0 = *(const half8_t*)(gv + tid*8);
            rv1 = *(const half8_t*)(gv + 2048 + tid*8);
        }
        const _Float16* kb = &lK[cur][0];
        const _Float16* vb = &lV[cur][0];
        f32x4 s[4];
        __builtin_amdgcn_s_setprio(1);
        #pragma unroll
        for (int t = 0; t < 4; ++t){
            half8_t k0 = *(const half8_t*)(kb + (t*2+0)*512 + lane*8);
            half8_t k1 = *(const half8_t*)(kb + (t*2+1)*512 + lane*8);
            f32x4 zz = {};
            zz = __builtin_amdgcn_mfma_f32_16x16x32_f16(k0, qf[0], zz, 0, 0, 0);
            zz = __builtin_amdgcn_mfma_f32_16x16x32_f16(k1, qf[1], zz, 0, 0, 0);
            s[t] = zz;
        }
        __builtin_amdgcn_s_setprio(0);
        half4_t pf[4];
        #pragma unroll
        for (int t = 0; t < 4; ++t){
            float e0 = EXP2F(s[t][0]*sm2 + bm2);
            float e1 = EXP2F(s[t][1]*sm2 + bm2);
            float e2 = EXP2F(s[t][2]*sm2 + bm2);
            float e3 = EXP2F(s[t][3]*sm2 + bm2);
            half2_t plo = PKRTZ(e0, e1), phi = PKRTZ(e2, e3);
            pf[t] = __builtin_shufflevector(plo, phi, 0, 1, 2, 3);
        }
        __builtin_amdgcn_s_setprio(1);
        #pragma unroll
        for (int t = 0; t < 4; ++t){
            half8_t vp0 = *(const half8_t*)(vb + (t*2+0)*512 + lane*8);
            half8_t vp1 = *(const half8_t*)(vb + (t*2+1)*512 + lane*8);
            half4_t v0 = __builtin_shufflevector(vp0, vp0, 0, 1, 2, 3);
            half4_t v1 = __builtin_shufflevector(vp0, vp0, 4, 5, 6, 7);
            half4_t v2 = __builtin_shufflevector(vp1, vp1, 0, 1, 2, 3);
            half4_t v3 = __builtin_shufflevector(vp1, vp1, 4, 5, 6, 7);
            acc5   = __builtin_amdgcn_mfma_f32_16x16x16f16(pf[t], ones4, acc5, 0, 0, 0);
            acc[0] = __builtin_amdgcn_mfma_f32_16x16x16f16(pf[t], v0, acc[0], 0, 0, 0);
            acc[1] = __builtin_amdgcn_mfma_f32_16x16x16f16(pf[t], v1, acc[1], 0, 0, 0);
            acc[2] = __builtin_amdgcn_mfma_f32_16x16x16f16(pf[t], v2, acc[2], 0, 0, 0);
            acc[3] = __builtin_amdgcn_mfma_f32_16x16x16f16(pf[t], v3, acc[3], 0, 0, 0);
        }
        __builtin_amdgcn_s_setprio(0);
        if (grp < SEQ/64 - 1){
            *(half8_t*)(&lK[cur^1][tid*8])        = rk0;
            *(half8_t*)(&lK[cur^1][2048 + tid*8]) = rk1;
            *(half8_t*)(&lV[cur^1][tid*8])        = rv0;
            *(half8_t*)(&lV[cur^1][2048 + tid*8]) = rv1;
        }
        __syncthreads();
        cur ^= 1;
    }

    if (l16 == 0){
        #pragma unroll
        for (int r = 0; r < 4; ++r)
            Ldenom[(size_t)bh*SEQ + q0 + 4*g + r] = acc5[r];
    }
    float invr[4];
    #pragma unroll
    for (int r = 0; r < 4; ++r)
        invr[r] = 1.0f / acc5[r];
    #pragma unroll
    for (int c = 0; c < 4; ++c)
        #pragma unroll
        for (int r = 0; r < 4; ++r)
            attended[(size_t)(b*SEQ + q0 + 4*g + r)*EMB + h*64 + 16*c + l16]
                = (_Float16)(acc[c][r] * invr[r]);
}

// ------------------------------------------- pass 2: softmax mean over heads
// (unchanged from R15 — verified)
__global__ __launch_bounds__(256) void mean_kernel(
    const _Float16* __restrict__ Qf, const _Float16* __restrict__ Kf,
    const float* __restrict__ emo_bias, const float* __restrict__ modv,
    const float* __restrict__ Ldenom, float* __restrict__ mean_out)
{
    const int tid  = threadIdx.x;
    const int w    = tid >> 6;
    const int lane = tid & 63;
    const int l16  = lane & 15;
    const int g    = lane >> 4;
    const int n    = blockIdx.x;
    const int work = (n & 7)*256 + (n >> 3);
    const int b    = work >> 9;
    const int ky   = (work >> 6) & 7;
    const int qt   = work & 63;
    const int q0   = qt * 32;
    const int k0w  = ky*256 + w*64;

    const float mod = modv[b];
    const float sm2 = 0.125f * mod * LOG2E;

    f32x4 msum[2][4] = {};
    for (int hp = 0; hp < HEADS/2; ++hp){
        const int h0 = 2*hp, h1 = 2*hp + 1;
        const size_t lo0 = (size_t)(b*HEADS + h0) * SEQ;
        const size_t lo1 = (size_t)(b*HEADS + h1) * SEQ;
        const size_t f0  = (size_t)(b*HEADS + h0) * 128;
        const size_t f1  = (size_t)(b*HEADS + h1) * 128;
        const float bm20 = emo_bias[h0] * mod * LOG2E;
        const float bm21 = emo_bias[h1] * mod * LOG2E;
        half8_t qA[2][2], qB[2][2];
        float elA[2][4], elB[2][4];
        #pragma unroll
        for (int T = 0; T < 2; ++T){
            const int qr = q0 + T*16;
            #pragma unroll
            for (int c = 0; c < 2; ++c){
                qA[T][c] = *(const half8_t*)(Qf + ((f0 + (qr>>4))*2 + c)*512 + lane*8);
                qB[T][c] = *(const half8_t*)(Qf + ((f1 + (qr>>4))*2 + c)*512 + lane*8);
            }
            #pragma unroll
            for (int r = 0; r < 4; ++r){
                elA[T][r] = bm20 - __log2f(Ldenom[lo0 + qr + 4*g + r]);
                elB[T][r] = bm21 - __log2f(Ldenom[lo1 + qr + 4*g + r]);
            }
        }
        #pragma unroll
        for (int j = 0; j < 4; ++j){
            const int kc = (k0w >> 4) + j;
            half8_t ka0 = *(const half8_t*)(Kf + ((f0 + kc)*2 + 0)*512 + lane*8);
            half8_t ka1 = *(const half8_t*)(Kf + ((f0 + kc)*2 + 1)*512 + lane*8);
            half8_t kb0 = *(const half8_t*)(Kf + ((f1 + kc)*2 + 0)*512 + lane*8);
            half8_t kb1 = *(const half8_t*)(Kf + ((f1 + kc)*2 + 1)*512 + lane*8);
            #pragma unroll
            for (int T = 0; T < 2; ++T){
                f32x4 sA = {}, sB = {};
                sA = __builtin_amdgcn_mfma_f32_16x16x32_f16(qA[T][0], ka0, sA, 0, 0, 0);
                sA = __builtin_amdgcn_mfma_f32_16x16x32_f16(qA[T][1], ka1, sA, 0, 0, 0);
                sB = __builtin_amdgcn_mfma_f32_16x16x32_f16(qB[T][0], kb0, sB, 0, 0, 0);
                sB = __builtin_amdgcn_mfma_f32_16x16x32_f16(qB[T][1], kb1, sB, 0, 0, 0);
                #pragma unroll
                for (int r = 0; r < 4; ++r)
                    msum[T][j][r] += EXP2F(sA[r]*sm2 + elA[T][r])
                                   + EXP2F(sB[r]*sm2 + elB[T][r]);
            }
        }
    }
    #pragma unroll
    for (int T = 0; T < 2; ++T)
        #pragma unroll
        for (int j = 0; j < 4; ++j)
            #pragma unroll
            for (int r = 0; r < 4; ++r)
                mean_out[(size_t)(b*SEQ + q0 + T*16 + 4*g + r)*SEQ + k0w + j*16 + l16]
                    = msum[T][j][r] * (1.0f/HEADS);
}

// ------------------------------------------------- output projection (LDS GEMM)
// 128x128 tile like qkv; A (f16) prefetched early, W loaded late.
__global__ __launch_bounds__(256) void outproj_kernel(
    const _Float16* __restrict__ A, const float* __restrict__ W,
    const float* __restrict__ bias, float* __restrict__ out)
{
    __shared__ _Float16 lA[128*64];
    __shared__ _Float16 lB[128*64];

    const int tid  = threadIdx.x;
    const int wid  = tid >> 6;
    const int lane = tid & 63;
    const int l16  = lane & 15;
    const int g    = lane >> 4;
    const int l7   = l16 & 7;
    const int mb = blockIdx.x;
    const int nb = blockIdx.y;
    const int wm = (wid >> 1)*64;
    const int wn = (wid & 1)*64;
    const int tR = tid >> 3;
    const int c8 = tid & 7;

    #pragma unroll
    for (int p = 0; p < 4; ++p){
        const int R = p*32 + tR;
        *(half8_t*)(lA + R*64 + ((c8 ^ (R & 7))*8)) =
            *(const half8_t*)(A + (size_t)(mb*128 + R)*EMB + c8*8);
    }
    #pragma unroll
    for (int p = 0; p < 4; ++p){
        const int R = p*32 + tR;
        *(half8_t*)(lB + R*64 + ((c8 ^ (R & 7))*8)) = cvt8(W + (size_t)(nb*128 + R)*EMB + c8*8);
    }
    __syncthreads();

    f32x4 acc[4][4] = {};
    for (int ks = 0; ks < 8; ++ks){
        half8_t ra[4];
        if (ks < 7){
            #pragma unroll
            for (int p = 0; p < 4; ++p)
                ra[p] = *(const half8_t*)(A + (size_t)(mb*128 + p*32 + tR)*EMB + (ks+1)*64 + c8*8);
        }
        __builtin_amdgcn_s_setprio(1);
        #pragma unroll
        for (int u = 0; u < 2; ++u){
            half8_t af[4], bf[4];
            #pragma unroll
            for (int i = 0; i < 4; ++i){
                const int rA = wm + i*16 + l16;
                af[i] = *(half8_t*)(lA + rA*64 + (((u*4 + g) ^ l7)*8));
            }
            #pragma unroll
            for (int j = 0; j < 4; ++j){
                const int rB = wn + j*16 + l16;
                bf[j] = *(half8_t*)(lB + rB*64 + (((u*4 + g) ^ l7)*8));
            }
            #pragma unroll
            for (int i = 0; i < 4; ++i)
                #pragma unroll
                for (int j = 0; j < 4; ++j)
                    acc[i][j] = __builtin_amdgcn_mfma_f32_16x16x32_f16(af[i], bf[j], acc[i][j], 0, 0, 0);
        }
        __builtin_amdgcn_s_setprio(0);
        __syncthreads();
        if (ks < 7){
            float4 wb0[4], wb1[4];
            #pragma unroll
            for (int p = 0; p < 4; ++p){
                const float* pw = W + (size_t)(nb*128 + p*32 + tR)*EMB + (ks+1)*64 + c8*8;
                wb0[p] = *(const float4*)pw;
                wb1[p] = *(const float4*)(pw + 4);
            }
            #pragma unroll
            for (int p = 0; p < 4; ++p){
                const int R = p*32 + tR;
                *(half8_t*)(lA + R*64 + ((c8 ^ (R & 7))*8)) = ra[p];
            }
            #pragma unroll
            for (int p = 0; p < 4; ++p){
                const int R = p*32 + tR;
                *(half8_t*)(lB + R*64 + ((c8 ^ (R & 7))*8)) = cvt8pk(wb0[p], wb1[p]);
            }
            __syncthreads();
        }
    }
    #pragma unroll
    for (int j = 0; j < 4; ++j){
        const int nn = nb*128 + wn + j*16 + l16;
        const float bn = bias[nn];
        #pragma unroll
        for (int i = 0; i < 4; ++i)
            #pragma unroll
            for (int r = 0; r < 4; ++r){
                const int m = mb*128 + wm + i*16 + 4*g + r;
                out[(size_t)m*EMB + nn] = acc[i][j][r] + bn;
            }
    }
}

// ---------------------------------------------------------------------- host
extern "C" void kernel_launch(void* const* d_in, const int* in_sizes, int n_in,
                              void* d_out, int out_size, void* d_ws, size_t ws_size,
                              hipStream_t stream)
{
    const float* query = (const float*)d_in[0];
    const float* key_  = (const float*)d_in[1];
    const float* value = (const float*)d_in[2];
    const float* emo   = (const float*)d_in[3];
    const float* Wq = (const float*)d_in[4];
    const float* bq = (const float*)d_in[5];
    const float* Wk = (const float*)d_in[6];
    const float* bk = (const float*)d_in[7];
    const float* Wv = (const float*)d_in[8];
    const float* bv = (const float*)d_in[9];
    const float* Wo = (const float*)d_in[10];
    const float* bo = (const float*)d_in[11];
    const float* emo_bias = (const float*)d_in[12];

    const size_t NTOK = (size_t)BATCH * SEQ * EMB;   // 4,194,304
    _Float16* ws       = (_Float16*)d_ws;
    _Float16* Qp       = ws;                          // ws usage: exactly 32 MiB
    _Float16* Kp       = ws + NTOK;
    _Float16* Vt       = ws + 2*NTOK;
    _Float16* attended = ws + 3*NTOK;

    float* out0     = (float*)d_out;
    float* mean_out = out0 + NTOK;
    float* Ldenom   = out0;                           // scratch in out0 region
    float* modv     = out0 + (size_t)BATCH*HEADS*SEQ; // overwritten by outproj

    mod_kernel<<<1, 64, 0, stream>>>(emo, modv);
    qkv_kernel<<<dim3(64, 4, 3), 256, 0, stream>>>(query, key_, value, Wq, Wk, Wv,
                                                   bq, bk, bv, Qp, Kp, Vt);
    pv_kernel<<<BATCH*HEADS*(SEQ/64), 256, 0, stream>>>(Qp, Kp, Vt, emo_bias, modv, attended, Ldenom);
    mean_kernel<<<BATCH*(SEQ/32)*(SEQ/256), 256, 0, stream>>>(Qp, Kp, emo_bias, modv, Ldenom, mean_out);
    outproj_kernel<<<dim3(64, 4), 256, 0, stream>>>(attended, Wo, bo, out0);
}

// Round 18
// 162.708 us; speedup vs baseline: 1.0432x; 1.0151x over previous
//
#include <hip/hip_runtime.h>

#define BATCH 4
#define SEQ   2048
#define EMB   512
#define HEADS 8
#define HD    64

typedef _Float16 half2_t __attribute__((ext_vector_type(2)));
typedef _Float16 half4_t __attribute__((ext_vector_type(4)));
typedef _Float16 half8_t __attribute__((ext_vector_type(8)));
typedef float    f32x4   __attribute__((ext_vector_type(4)));

#if __has_builtin(__builtin_amdgcn_exp2f)
#define EXP2F(x) __builtin_amdgcn_exp2f(x)
#else
#define EXP2F(x) exp2f(x)
#endif
#define LOG2E 1.44269504088896f

#define PKRTZ(a, b) __builtin_bit_cast(half2_t, __builtin_amdgcn_cvt_pkrtz((a), (b)))

// ---------------------------------------------------------------- mod factor
__global__ void mod_kernel(const float* __restrict__ emo, float* __restrict__ modv){
    int lane = threadIdx.x;                 // 64 threads, 1 wave
    for (int b = 0; b < BATCH; ++b){
        float v = emo[b*64 + lane];
        #pragma unroll
        for (int off = 32; off >= 1; off >>= 1) v += __shfl_xor(v, off, 64);
        if (lane == 0){
            float mean = v * (1.0f/64.0f);
            float sig  = 1.0f/(1.0f + __expf(-mean));
            modv[b] = 0.5f + 0.5f*sig;
        }
    }
}

// packed f32->f16 converts (RTZ; staging-only, <=1 ulp f16)
__device__ inline half8_t cvt8pk(float4 v0, float4 v1){
    half2_t p0 = PKRTZ(v0.x, v0.y), p1 = PKRTZ(v0.z, v0.w);
    half2_t p2 = PKRTZ(v1.x, v1.y), p3 = PKRTZ(v1.z, v1.w);
    half4_t a = __builtin_shufflevector(p0, p1, 0, 1, 2, 3);
    half4_t b = __builtin_shufflevector(p2, p3, 0, 1, 2, 3);
    return __builtin_shufflevector(a, b, 0, 1, 2, 3, 4, 5, 6, 7);
}
__device__ inline half8_t cvt8(const float* p){
    return cvt8pk(*(const float4*)p, *(const float4*)(p + 4));
}

// --------------------------------------- QKV projections, one launch (z=0,1,2)
// Single 24KB XOR-swizzled LDS (6 blocks/CU) + EARLY register prefetch.
// (R13/R15-verified best variant; 128x128-tile variant measured SLOWER.)
__global__ __launch_bounds__(256) void qkv_kernel(
    const float* __restrict__ X0, const float* __restrict__ X1, const float* __restrict__ X2,
    const float* __restrict__ W0, const float* __restrict__ W1, const float* __restrict__ W2,
    const float* __restrict__ b0, const float* __restrict__ b1, const float* __restrict__ b2,
    _Float16* __restrict__ o0, _Float16* __restrict__ o1, _Float16* __restrict__ o2)
{
    const int z = blockIdx.z;
    const float* X    = (z==0) ? X0 : (z==1) ? X1 : X2;
    const float* W    = (z==0) ? W0 : (z==1) ? W1 : W2;
    const float* bias = (z==0) ? b0 : (z==1) ? b1 : b2;
    _Float16*  out    = (z==0) ? o0 : (z==1) ? o1 : o2;

    __shared__ _Float16 lA[128*64];       // 16 KB row-major, swizzled chunks
    __shared__ _Float16 lB[64*64];        //  8 KB

    const int tid  = threadIdx.x;
    const int wid  = tid >> 6;
    const int lane = tid & 63;
    const int l16  = lane & 15;
    const int g    = lane >> 4;
    const int l7   = l16 & 7;
    const int mb = blockIdx.x;
    const int nb = blockIdx.y;
    const int wm = (wid >> 1)*64;
    const int wn = (wid & 1)*32;
    const int tR = tid >> 3;
    const int c8 = tid & 7;

    #pragma unroll
    for (int p = 0; p < 4; ++p){
        const int R = p*32 + tR;
        *(half8_t*)(lA + R*64 + ((c8 ^ (R & 7))*8)) = cvt8(X + (size_t)(mb*128 + R)*EMB + c8*8);
    }
    #pragma unroll
    for (int p = 0; p < 2; ++p){
        const int R = p*32 + tR;
        *(half8_t*)(lB + R*64 + ((c8 ^ (R & 7))*8)) = cvt8(W + (size_t)(nb*64 + R)*EMB + c8*8);
    }
    __syncthreads();

    f32x4 acc[4][2] = {};
    for (int ks = 0; ks < 8; ++ks){
        float4 xa0[4], xa1[4], wb0[2], wb1[2];
        if (ks < 7){
            #pragma unroll
            for (int p = 0; p < 4; ++p){
                const float* px = X + (size_t)(mb*128 + p*32 + tR)*EMB + (ks+1)*64 + c8*8;
                xa0[p] = *(const float4*)px;
                xa1[p] = *(const float4*)(px + 4);
            }
            #pragma unroll
            for (int p = 0; p < 2; ++p){
                const float* pw = W + (size_t)(nb*64 + p*32 + tR)*EMB + (ks+1)*64 + c8*8;
                wb0[p] = *(const float4*)pw;
                wb1[p] = *(const float4*)(pw + 4);
            }
        }
        __builtin_amdgcn_s_setprio(1);
        #pragma unroll
        for (int u = 0; u < 2; ++u){
            half8_t af[4], bf[2];
            #pragma unroll
            for (int i = 0; i < 4; ++i){
                const int rA = wm + i*16 + l16;
                af[i] = *(half8_t*)(lA + rA*64 + (((u*4 + g) ^ l7)*8));
            }
            #pragma unroll
            for (int j = 0; j < 2; ++j){
                const int rB = wn + j*16 + l16;
                bf[j] = *(half8_t*)(lB + rB*64 + (((u*4 + g) ^ l7)*8));
            }
            #pragma unroll
            for (int i = 0; i < 4; ++i)
                #pragma unroll
                for (int j = 0; j < 2; ++j)
                    acc[i][j] = __builtin_amdgcn_mfma_f32_16x16x32_f16(af[i], bf[j], acc[i][j], 0, 0, 0);
        }
        __builtin_amdgcn_s_setprio(0);
        __syncthreads();          // all reads of the buffer done
        if (ks < 7){
            #pragma unroll
            for (int p = 0; p < 4; ++p){
                const int R = p*32 + tR;
                *(half8_t*)(lA + R*64 + ((c8 ^ (R & 7))*8)) = cvt8pk(xa0[p], xa1[p]);
            }
            #pragma unroll
            for (int p = 0; p < 2; ++p){
                const int R = p*32 + tR;
                *(half8_t*)(lB + R*64 + ((c8 ^ (R & 7))*8)) = cvt8pk(wb0[p], wb1[p]);
            }
            __syncthreads();      // buffer refilled
        }
    }
    // ---- store (fragment-major out, mapping identical to R10-R15)
    #pragma unroll
    for (int j = 0; j < 2; ++j){
        const int nn  = nb*64 + wn + j*16 + l16;
        const float bn = bias[nn];
        const int h = nn >> 6, d = nn & 63;
        #pragma unroll
        for (int i = 0; i < 4; ++i){
            #pragma unroll
            for (int r = 0; r < 4; ++r){
                const int m  = mb*128 + wm + i*16 + 4*g + r;
                const int bb2 = m >> 11, s = m & 2047;
                const int bh  = bb2*8 + h;
                const float v = acc[i][j][r] + bn;
                size_t idx;
                if (z == 2)
                    idx = ((size_t)(bh*128 + (s>>4))*2 + (d>>5))*512
                        + (size_t)((((s>>2)&3)*16 + (d&15))*8 + ((d>>4)&1)*4 + (s&3));
                else
                    idx = ((size_t)(bh*128 + (s>>4))*2 + (d>>5))*512
                        + (size_t)((((d>>3)&3)*16 + (s&15))*8 + (d&7));
                out[idx] = (_Float16)v;
            }
        }
    }
}

// ---------------------------------------------------- pass 1: PV + denominators
// R15-verified best: lane-linear dbuf staging + phase-split + setprio +
// rowsum-by-MFMA (acc5 with ones-column gives L on the matrix pipe).
__global__ __launch_bounds__(256) void pv_kernel(
    const _Float16* __restrict__ Qf, const _Float16* __restrict__ Kf,
    const _Float16* __restrict__ Vf, const float* __restrict__ emo_bias,
    const float* __restrict__ modv, _Float16* __restrict__ attended,
    float* __restrict__ Ldenom)
{
    __shared__ _Float16 lK[2][4096];      // 2 x 8 KB
    __shared__ _Float16 lV[2][4096];      // 2 x 8 KB

    const int tid  = threadIdx.x;
    const int lane = tid & 63;
    const int l16  = lane & 15;
    const int g    = lane >> 4;
    const int n    = blockIdx.x;
    const int work = (n & 7)*128 + (n >> 3);   // bijective for 1024 blocks
    const int qt   = work & 31;
    const int bh   = work >> 5;
    const int b    = bh >> 3, h = bh & 7;
    const int q0   = qt*64 + (tid >> 6)*16;

    const float mod = modv[b];
    const float sm2 = 0.125f * mod * LOG2E;
    const float bm2 = emo_bias[h] * mod * LOG2E;

    const size_t fB = (size_t)bh * 128;

    half8_t qf[2];
    #pragma unroll
    for (int c = 0; c < 2; ++c)
        qf[c] = *(const half8_t*)(Qf + ((fB + (q0>>4))*2 + c)*512 + lane*8);

    {   // prologue: lane-linear staging of group 0
        const _Float16* gk = Kf + fB*1024;
        const _Float16* gv = Vf + fB*1024;
        *(half8_t*)(&lK[0][tid*8])        = *(const half8_t*)(gk + tid*8);
        *(half8_t*)(&lK[0][2048 + tid*8]) = *(const half8_t*)(gk + 2048 + tid*8);
        *(half8_t*)(&lV[0][tid*8])        = *(const half8_t*)(gv + tid*8);
        *(half8_t*)(&lV[0][2048 + tid*8]) = *(const half8_t*)(gv + 2048 + tid*8);
    }
    __syncthreads();

    const half4_t ones4 = {(_Float16)1.0f, (_Float16)1.0f, (_Float16)1.0f, (_Float16)1.0f};
    f32x4 acc[4] = {};
    f32x4 acc5 = {};                      // rowsums (softmax denominators)
    int cur = 0;
    for (int grp = 0; grp < SEQ/64; ++grp){
        half8_t rk0, rk1, rv0, rv1;
        if (grp < SEQ/64 - 1){
            const _Float16* gk = Kf + (fB + (size_t)(grp+1)*4)*1024;
            const _Float16* gv = Vf + (fB + (size_t)(grp+1)*4)*1024;
            rk0 = *(const half8_t*)(gk + tid*8);
            rk1 = *(const half8_t*)(gk + 2048 + tid*8);
            rv0 = *(const half8_t*)(gv + tid*8);
            rv1 = *(const half8_t*)(gv + 2048 + tid*8);
        }
        const _Float16* kb = &lK[cur][0];
        const _Float16* vb = &lV[cur][0];
        f32x4 s[4];
        __builtin_amdgcn_s_setprio(1);
        #pragma unroll
        for (int t = 0; t < 4; ++t){
            half8_t k0 = *(const half8_t*)(kb + (t*2+0)*512 + lane*8);
            half8_t k1 = *(const half8_t*)(kb + (t*2+1)*512 + lane*8);
            f32x4 zz = {};
            zz = __builtin_amdgcn_mfma_f32_16x16x32_f16(k0, qf[0], zz, 0, 0, 0);
            zz = __builtin_amdgcn_mfma_f32_16x16x32_f16(k1, qf[1], zz, 0, 0, 0);
            s[t] = zz;
        }
        __builtin_amdgcn_s_setprio(0);
        half4_t pf[4];
        #pragma unroll
        for (int t = 0; t < 4; ++t){
            float e0 = EXP2F(s[t][0]*sm2 + bm2);
            float e1 = EXP2F(s[t][1]*sm2 + bm2);
            float e2 = EXP2F(s[t][2]*sm2 + bm2);
            float e3 = EXP2F(s[t][3]*sm2 + bm2);
            half2_t plo = PKRTZ(e0, e1), phi = PKRTZ(e2, e3);
            pf[t] = __builtin_shufflevector(plo, phi, 0, 1, 2, 3);
        }
        __builtin_amdgcn_s_setprio(1);
        #pragma unroll
        for (int t = 0; t < 4; ++t){
            half8_t vp0 = *(const half8_t*)(vb + (t*2+0)*512 + lane*8);
            half8_t vp1 = *(const half8_t*)(vb + (t*2+1)*512 + lane*8);
            half4_t v0 = __builtin_shufflevector(vp0, vp0, 0, 1, 2, 3);
            half4_t v1 = __builtin_shufflevector(vp0, vp0, 4, 5, 6, 7);
            half4_t v2 = __builtin_shufflevector(vp1, vp1, 0, 1, 2, 3);
            half4_t v3 = __builtin_shufflevector(vp1, vp1, 4, 5, 6, 7);
            acc5   = __builtin_amdgcn_mfma_f32_16x16x16f16(pf[t], ones4, acc5, 0, 0, 0);
            acc[0] = __builtin_amdgcn_mfma_f32_16x16x16f16(pf[t], v0, acc[0], 0, 0, 0);
            acc[1] = __builtin_amdgcn_mfma_f32_16x16x16f16(pf[t], v1, acc[1], 0, 0, 0);
            acc[2] = __builtin_amdgcn_mfma_f32_16x16x16f16(pf[t], v2, acc[2], 0, 0, 0);
            acc[3] = __builtin_amdgcn_mfma_f32_16x16x16f16(pf[t], v3, acc[3], 0, 0, 0);
        }
        __builtin_amdgcn_s_setprio(0);
        if (grp < SEQ/64 - 1){
            *(half8_t*)(&lK[cur^1][tid*8])        = rk0;
            *(half8_t*)(&lK[cur^1][2048 + tid*8]) = rk1;
            *(half8_t*)(&lV[cur^1][tid*8])        = rv0;
            *(half8_t*)(&lV[cur^1][2048 + tid*8]) = rv1;
        }
        __syncthreads();
        cur ^= 1;
    }

    // acc5[r] = L(q0+4g+r), identical across l16.
    if (l16 == 0){
        #pragma unroll
        for (int r = 0; r < 4; ++r)
            Ldenom[(size_t)bh*SEQ + q0 + 4*g + r] = acc5[r];
    }
    float invr[4];
    #pragma unroll
    for (int r = 0; r < 4; ++r)
        invr[r] = 1.0f / acc5[r];
    #pragma unroll
    for (int c = 0; c < 4; ++c)
        #pragma unroll
        for (int r = 0; r < 4; ++r)
            attended[(size_t)(b*SEQ + q0 + 4*g + r)*EMB + h*64 + 16*c + l16]
                = (_Float16)(acc[c][r] * invr[r]);
}

// ------------------------------------------- pass 2: softmax mean over heads
// R15-verified: 32 q-rows (2 tiles) per block, K-frag loads shared by tiles,
// normalization folded into the exponent (p = 2^(s*sm2 + bm2 - log2 L)).
__global__ __launch_bounds__(256) void mean_kernel(
    const _Float16* __restrict__ Qf, const _Float16* __restrict__ Kf,
    const float* __restrict__ emo_bias, const float* __restrict__ modv,
    const float* __restrict__ Ldenom, float* __restrict__ mean_out)
{
    const int tid  = threadIdx.x;
    const int w    = tid >> 6;
    const int lane = tid & 63;
    const int l16  = lane & 15;
    const int g    = lane >> 4;
    const int n    = blockIdx.x;
    const int work = (n & 7)*256 + (n >> 3);
    const int b    = work >> 9;
    const int ky   = (work >> 6) & 7;
    const int qt   = work & 63;
    const int q0   = qt * 32;
    const int k0w  = ky*256 + w*64;

    const float mod = modv[b];
    const float sm2 = 0.125f * mod * LOG2E;

    f32x4 msum[2][4] = {};
    for (int hp = 0; hp < HEADS/2; ++hp){
        const int h0 = 2*hp, h1 = 2*hp + 1;
        const size_t lo0 = (size_t)(b*HEADS + h0) * SEQ;
        const size_t lo1 = (size_t)(b*HEADS + h1) * SEQ;
        const size_t f0  = (size_t)(b*HEADS + h0) * 128;
        const size_t f1  = (size_t)(b*HEADS + h1) * 128;
        const float bm20 = emo_bias[h0] * mod * LOG2E;
        const float bm21 = emo_bias[h1] * mod * LOG2E;
        half8_t qA[2][2], qB[2][2];
        float elA[2][4], elB[2][4];
        #pragma unroll
        for (int T = 0; T < 2; ++T){
            const int qr = q0 + T*16;
            #pragma unroll
            for (int c = 0; c < 2; ++c){
                qA[T][c] = *(const half8_t*)(Qf + ((f0 + (qr>>4))*2 + c)*512 + lane*8);
                qB[T][c] = *(const half8_t*)(Qf + ((f1 + (qr>>4))*2 + c)*512 + lane*8);
            }
            #pragma unroll
            for (int r = 0; r < 4; ++r){
                elA[T][r] = bm20 - __log2f(Ldenom[lo0 + qr + 4*g + r]);
                elB[T][r] = bm21 - __log2f(Ldenom[lo1 + qr + 4*g + r]);
            }
        }
        #pragma unroll
        for (int j = 0; j < 4; ++j){
            const int kc = (k0w >> 4) + j;
            half8_t ka0 = *(const half8_t*)(Kf + ((f0 + kc)*2 + 0)*512 + lane*8);
            half8_t ka1 = *(const half8_t*)(Kf + ((f0 + kc)*2 + 1)*512 + lane*8);
            half8_t kb0 = *(const half8_t*)(Kf + ((f1 + kc)*2 + 0)*512 + lane*8);
            half8_t kb1 = *(const half8_t*)(Kf + ((f1 + kc)*2 + 1)*512 + lane*8);
            #pragma unroll
            for (int T = 0; T < 2; ++T){
                f32x4 sA = {}, sB = {};
                sA = __builtin_amdgcn_mfma_f32_16x16x32_f16(qA[T][0], ka0, sA, 0, 0, 0);
                sA = __builtin_amdgcn_mfma_f32_16x16x32_f16(qA[T][1], ka1, sA, 0, 0, 0);
                sB = __builtin_amdgcn_mfma_f32_16x16x32_f16(qB[T][0], kb0, sB, 0, 0, 0);
                sB = __builtin_amdgcn_mfma_f32_16x16x32_f16(qB[T][1], kb1, sB, 0, 0, 0);
                #pragma unroll
                for (int r = 0; r < 4; ++r)
                    msum[T][j][r] += EXP2F(sA[r]*sm2 + elA[T][r])
                                   + EXP2F(sB[r]*sm2 + elB[T][r]);
            }
        }
    }
    #pragma unroll
    for (int T = 0; T < 2; ++T)
        #pragma unroll
        for (int j = 0; j < 4; ++j)
            #pragma unroll
            for (int r = 0; r < 4; ++r)
                mean_out[(size_t)(b*SEQ + q0 + T*16 + 4*g + r)*SEQ + k0w + j*16 + l16]
                    = msum[T][j][r] * (1.0f/HEADS);
}

// ------------------------------------------------- output projection (LDS GEMM)
// R15-verified: single 24KB buffer + early reg prefetch; A is f16 (no cvt).
__global__ __launch_bounds__(256) void outproj_kernel(
    const _Float16* __restrict__ A, const float* __restrict__ W,
    const float* __restrict__ bias, float* __restrict__ out)
{
    __shared__ _Float16 lA[128*64];
    __shared__ _Float16 lB[64*64];

    const int tid  = threadIdx.x;
    const int wid  = tid >> 6;
    const int lane = tid & 63;
    const int l16  = lane & 15;
    const int g    = lane >> 4;
    const int l7   = l16 & 7;
    const int mb = blockIdx.x;
    const int nb = blockIdx.y;
    const int wm = (wid >> 1)*64;
    const int wn = (wid & 1)*32;
    const int tR = tid >> 3;
    const int c8 = tid & 7;

    #pragma unroll
    for (int p = 0; p < 4; ++p){
        const int R = p*32 + tR;
        *(half8_t*)(lA + R*64 + ((c8 ^ (R & 7))*8)) =
            *(const half8_t*)(A + (size_t)(mb*128 + R)*EMB + c8*8);
    }
    #pragma unroll
    for (int p = 0; p < 2; ++p){
        const int R = p*32 + tR;
        *(half8_t*)(lB + R*64 + ((c8 ^ (R & 7))*8)) = cvt8(W + (size_t)(nb*64 + R)*EMB + c8*8);
    }
    __syncthreads();

    f32x4 acc[4][2] = {};
    for (int ks = 0; ks < 8; ++ks){
        half8_t ra[4];
        float4 wb0[2], wb1[2];
        if (ks < 7){
            #pragma unroll
            for (int p = 0; p < 4; ++p)
                ra[p] = *(const half8_t*)(A + (size_t)(mb*128 + p*32 + tR)*EMB + (ks+1)*64 + c8*8);
            #pragma unroll
            for (int p = 0; p < 2; ++p){
                const float* pw = W + (size_t)(nb*64 + p*32 + tR)*EMB + (ks+1)*64 + c8*8;
                wb0[p] = *(const float4*)pw;
                wb1[p] = *(const float4*)(pw + 4);
            }
        }
        __builtin_amdgcn_s_setprio(1);
        #pragma unroll
        for (int u = 0; u < 2; ++u){
            half8_t af[4], bf[2];
            #pragma unroll
            for (int i = 0; i < 4; ++i){
                const int rA = wm + i*16 + l16;
                af[i] = *(half8_t*)(lA + rA*64 + (((u*4 + g) ^ l7)*8));
            }
            #pragma unroll
            for (int j = 0; j < 2; ++j){
                const int rB = wn + j*16 + l16;
                bf[j] = *(half8_t*)(lB + rB*64 + (((u*4 + g) ^ l7)*8));
            }
            #pragma unroll
            for (int i = 0; i < 4; ++i)
                #pragma unroll
                for (int j = 0; j < 2; ++j)
                    acc[i][j] = __builtin_amdgcn_mfma_f32_16x16x32_f16(af[i], bf[j], acc[i][j], 0, 0, 0);
        }
        __builtin_amdgcn_s_setprio(0);
        __syncthreads();
        if (ks < 7){
            #pragma unroll
            for (int p = 0; p < 4; ++p){
                const int R = p*32 + tR;
                *(half8_t*)(lA + R*64 + ((c8 ^ (R & 7))*8)) = ra[p];
            }
            #pragma unroll
            for (int p = 0; p < 2; ++p){
                const int R = p*32 + tR;
                *(half8_t*)(lB + R*64 + ((c8 ^ (R & 7))*8)) = cvt8pk(wb0[p], wb1[p]);
            }
            __syncthreads();
        }
    }
    #pragma unroll
    for (int j = 0; j < 2; ++j){
        const int nn = nb*64 + wn + j*16 + l16;
        const float bn = bias[nn];
        #pragma unroll
        for (int i = 0; i < 4; ++i)
            #pragma unroll
            for (int r = 0; r < 4; ++r){
                const int m = mb*128 + wm + i*16 + 4*g + r;
                out[(size_t)m*EMB + nn] = acc[i][j][r] + bn;
            }
    }
}

// ---------------------------------------------------------------------- host
extern "C" void kernel_launch(void* const* d_in, const int* in_sizes, int n_in,
                              void* d_out, int out_size, void* d_ws, size_t ws_size,
                              hipStream_t stream)
{
    const float* query = (const float*)d_in[0];
    const float* key_  = (const float*)d_in[1];
    const float* value = (const float*)d_in[2];
    const float* emo   = (const float*)d_in[3];
    const float* Wq = (const float*)d_in[4];
    const float* bq = (const float*)d_in[5];
    const float* Wk = (const float*)d_in[6];
    const float* bk = (const float*)d_in[7];
    const float* Wv = (const float*)d_in[8];
    const float* bv = (const float*)d_in[9];
    const float* Wo = (const float*)d_in[10];
    const float* bo = (const float*)d_in[11];
    const float* emo_bias = (const float*)d_in[12];

    const size_t NTOK = (size_t)BATCH * SEQ * EMB;   // 4,194,304
    _Float16* ws       = (_Float16*)d_ws;
    _Float16* Qp       = ws;                          // ws usage: exactly 32 MiB
    _Float16* Kp       = ws + NTOK;
    _Float16* Vt       = ws + 2*NTOK;
    _Float16* attended = ws + 3*NTOK;

    float* out0     = (float*)d_out;
    float* mean_out = out0 + NTOK;
    float* Ldenom   = out0;                           // scratch in out0 region
    float* modv     = out0 + (size_t)BATCH*HEADS*SEQ; // overwritten by outproj

    mod_kernel<<<1, 64, 0, stream>>>(emo, modv);
    qkv_kernel<<<dim3(64, 8, 3), 256, 0, stream>>>(query, key_, value, Wq, Wk, Wv,
                                                   bq, bk, bv, Qp, Kp, Vt);
    pv_kernel<<<BATCH*HEADS*(SEQ/64), 256, 0, stream>>>(Qp, Kp, Vt, emo_bias, modv, attended, Ldenom);
    mean_kernel<<<BATCH*(SEQ/32)*(SEQ/256), 256, 0, stream>>>(Qp, Kp, emo_bias, modv, Ldenom, mean_out);
    outproj_kernel<<<dim3(64, 8), 256, 0, stream>>>(attended, Wo, bo, out0);
}